// Round 1
// baseline (2015.731 us; speedup 1.0000x reference)
//
#include <hip/hip_runtime.h>
#include <cstdint>
#include <cstddef>

#define D_DIM 2048
#define F_DIM 8192
#define M_DIM 8192   // 4 * 2048 tokens
#define SCALING 2.0f
#define GAMMA 0.1f

typedef __bf16 bf16x8 __attribute__((ext_vector_type(8)));
typedef float f32x4 __attribute__((ext_vector_type(4)));
typedef unsigned short ushort_t;

__device__ __forceinline__ unsigned short f2bf(float f) {
  unsigned int u = __float_as_uint(f);
  u += 0x7FFF + ((u >> 16) & 1);  // round-to-nearest-even
  return (unsigned short)(u >> 16);
}

__device__ __forceinline__ float era_f(float x) {
  // gelu_tanh(x) + GAMMA * softplus(x)
  float x3 = x * x * x;
  float inner = 0.7978845608028654f * (x + 0.044715f * x3);
  float e = __expf(2.0f * inner);
  float th = 1.0f - 2.0f / (e + 1.0f);       // tanh(inner), inf-safe
  float gelu = 0.5f * x * (1.0f + th);
  float sp = fmaxf(x, 0.0f) + __logf(1.0f + __expf(-fabsf(x)));
  return gelu + GAMMA * sp;
}

// ---------------- prep kernels ----------------

__global__ void convert_x(const float* __restrict__ in, ushort_t* __restrict__ out, int n) {
  int i = (blockIdx.x * 256 + threadIdx.x) * 4;
  if (i >= n) return;
  float4 v = *(const float4*)(in + i);
  out[i + 0] = f2bf(v.x);
  out[i + 1] = f2bf(v.y);
  out[i + 2] = f2bf(v.z);
  out[i + 3] = f2bf(v.w);
}

// in: fp32 [K][N] row-major  ->  out: bf16 [N][K]
__global__ void transpose_w(const float* __restrict__ in, ushort_t* __restrict__ out,
                            int K, int N) {
  __shared__ float tile[32][33];
  int k0 = blockIdx.y * 32, n0 = blockIdx.x * 32;
  int tr = threadIdx.x >> 5, tc = threadIdx.x & 31;
#pragma unroll
  for (int i = 0; i < 32; i += 8)
    tile[tr + i][tc] = in[(size_t)(k0 + tr + i) * N + n0 + tc];
  __syncthreads();
#pragma unroll
  for (int i = 0; i < 32; i += 8)
    out[(size_t)(n0 + tr + i) * K + k0 + tc] = f2bf(tile[tc][tr + i]);
}

// Wup fp32 [16][F] -> bf16 [F][32], k>=16 zero-padded
__global__ void pad_small(const float* __restrict__ in, ushort_t* __restrict__ out, int F) {
  int idx = blockIdx.x * 256 + threadIdx.x;  // F*32 total
  int f = idx >> 5, k = idx & 31;
  float v = (k < 16) ? in[(size_t)k * F + f] : 0.0f;
  out[idx] = f2bf(v);
}

// xd = SCALING * (x @ Wdn + bdn), stored bf16 [M][32] zero-padded; both g and u branches
__global__ void lora_down(const float* __restrict__ x,
                          const float* __restrict__ Wgd, const float* __restrict__ bgd,
                          const float* __restrict__ Wud, const float* __restrict__ bud,
                          ushort_t* __restrict__ xdg, ushort_t* __restrict__ xdu) {
  int row = blockIdx.x * 8 + (threadIdx.x >> 5);
  int c = threadIdx.x & 31;
  bool isG = (c < 16);
  int col = c & 15;
  const float* W = isG ? Wgd : Wud;
  const float* xr = x + (size_t)row * D_DIM;
  float acc = 0.0f;
  for (int k = 0; k < D_DIM; ++k)
    acc = fmaf(xr[k], W[k * 16 + col], acc);
  float b = isG ? bgd[col] : bud[col];
  ushort_t v = f2bf(SCALING * (acc + b));
  ushort_t* dst = isG ? xdg : xdu;
  dst[row * 32 + col] = v;
  dst[row * 32 + 16 + col] = 0;  // zero pad lanes k=16..31
}

// ---------------- GEMM helpers ----------------

// Direct global->LDS DMA, 16B per lane. LDS dest must be the WAVE-UNIFORM base;
// HW stores lane i at (base + i*16B). Global src is per-lane.
__device__ __forceinline__ void gload16(const ushort_t* g, ushort_t* l) {
  __builtin_amdgcn_global_load_lds(
      (__attribute__((address_space(1))) void*)g,
      (__attribute__((address_space(3))) void*)l, 16, 0, 0);
}

__device__ __forceinline__ bf16x8 frag_ld(const ushort_t* p) {
  union { uint4 u; bf16x8 v; } un;
  un.u = *(const uint4*)p;
  return un.v;
}

// Linear LDS tile [128][32] bf16 (64B rows, 4x16B chunks/row).
// XOR swizzle: LDS slot (row, c) holds global chunk (row, c ^ ((row>>1)&3)).
// Write side: pre-swizzle the GLOBAL source chunk (DMA dest stays linear).
// Read side: logical chunk q lives in slot q ^ ((row>>1)&3).
// Read bank pattern: 16*ml + 4*((ml>>1)&3) mod 32 -> 8 banks x 2 lanes = 2-way = free.

// ---------------- fused gate+up GEMM ----------------
// h_g = x@Wg + bg + xdg_s@Wgu + s*bgu ;  h_u analogous ;  t = ERA(h_g)*h_u (bf16)
__global__ __launch_bounds__(256) void gemm_gateup(
    const ushort_t* __restrict__ xbf, const ushort_t* __restrict__ Wgt,
    const ushort_t* __restrict__ Wut, const ushort_t* __restrict__ Wgup,
    const ushort_t* __restrict__ Wuup, const ushort_t* __restrict__ xdg,
    const ushort_t* __restrict__ xdu,
    const float* __restrict__ bg, const float* __restrict__ bgu,
    const float* __restrict__ bu, const float* __restrict__ buu,
    ushort_t* __restrict__ tout) {
  __shared__ __align__(16) ushort_t xs[128 * 32];
  __shared__ __align__(16) ushort_t wgs[128 * 32];
  __shared__ __align__(16) ushort_t wus[128 * 32];
  const int f0 = blockIdx.x * 128;
  const int m0 = blockIdx.y * 128;
  const int t = threadIdx.x;
  const int w = t >> 6, lane = t & 63;
  const int wm = w >> 1, wn = w & 1;
  const int ml = lane & 15, q = lane >> 4;

  // staging addressing: round p covers rows [p*64, p*64+64); thread t -> row t>>2, chunk t&3
  const int srow = t >> 2;                         // 0..63
  const int cs = ((t & 3) ^ ((srow >> 1) & 3)) * 8;  // swizzled chunk offset (ushorts)
  // read addressing: slot offset is a per-thread constant (frag base rows are x16)
  const int slotq = (q ^ ((ml >> 1) & 3)) * 8;

  // wave-uniform LDS dst bases (ushort offsets): round0 = w*512, round1 = 2048 + w*512
  ushort_t* xd0 = xs + w * 512;   ushort_t* xd1 = xs + 2048 + w * 512;
  ushort_t* gd0 = wgs + w * 512;  ushort_t* gd1 = wgs + 2048 + w * 512;
  ushort_t* ud0 = wus + w * 512;  ushort_t* ud1 = wus + 2048 + w * 512;

  const f32x4 zero4 = {0.f, 0.f, 0.f, 0.f};
  f32x4 accg[4][4], accu[4][4];
#pragma unroll
  for (int i = 0; i < 4; ++i)
#pragma unroll
    for (int j = 0; j < 4; ++j) { accg[i][j] = zero4; accu[i][j] = zero4; }

  const ushort_t* xsrc0 = xbf + (size_t)(m0 + srow) * D_DIM + cs;
  const ushort_t* xsrc1 = xsrc0 + (size_t)64 * D_DIM;
  const ushort_t* gsrc0 = Wgt + (size_t)(f0 + srow) * D_DIM + cs;
  const ushort_t* gsrc1 = gsrc0 + (size_t)64 * D_DIM;
  const ushort_t* usrc0 = Wut + (size_t)(f0 + srow) * D_DIM + cs;
  const ushort_t* usrc1 = usrc0 + (size_t)64 * D_DIM;

  for (int kt = 0; kt < D_DIM / 32; ++kt) {
    const int ko = kt * 32;
    __syncthreads();
    gload16(xsrc0 + ko, xd0);  gload16(xsrc1 + ko, xd1);
    gload16(gsrc0 + ko, gd0);  gload16(gsrc1 + ko, gd1);
    gload16(usrc0 + ko, ud0);  gload16(usrc1 + ko, ud1);
    __syncthreads();
    bf16x8 af[4], bgf[4], buf2[4];
#pragma unroll
    for (int i = 0; i < 4; ++i) {
      af[i]   = frag_ld(xs  + (wm * 64 + i * 16 + ml) * 32 + slotq);
      bgf[i]  = frag_ld(wgs + (wn * 64 + i * 16 + ml) * 32 + slotq);
      buf2[i] = frag_ld(wus + (wn * 64 + i * 16 + ml) * 32 + slotq);
    }
#pragma unroll
    for (int mi = 0; mi < 4; ++mi)
#pragma unroll
      for (int ni = 0; ni < 4; ++ni) {
        accg[mi][ni] = __builtin_amdgcn_mfma_f32_16x16x32_bf16(af[mi], bgf[ni], accg[mi][ni], 0, 0, 0);
        accu[mi][ni] = __builtin_amdgcn_mfma_f32_16x16x32_bf16(af[mi], buf2[ni], accu[mi][ni], 0, 0, 0);
      }
  }

  // LoRA gate step (K=32, upper 16 zero-padded); tiles are [rows][32] so ldK = 32
  __syncthreads();
  gload16(xdg + ((size_t)m0 + srow) * 32 + cs, xd0);
  gload16(xdg + ((size_t)m0 + srow + 64) * 32 + cs, xd1);
  gload16(Wgup + ((size_t)f0 + srow) * 32 + cs, gd0);
  gload16(Wgup + ((size_t)f0 + srow + 64) * 32 + cs, gd1);
  __syncthreads();
  {
    bf16x8 af[4], bgf[4];
#pragma unroll
    for (int i = 0; i < 4; ++i) {
      af[i]  = frag_ld(xs  + (wm * 64 + i * 16 + ml) * 32 + slotq);
      bgf[i] = frag_ld(wgs + (wn * 64 + i * 16 + ml) * 32 + slotq);
    }
#pragma unroll
    for (int mi = 0; mi < 4; ++mi)
#pragma unroll
      for (int ni = 0; ni < 4; ++ni)
        accg[mi][ni] = __builtin_amdgcn_mfma_f32_16x16x32_bf16(af[mi], bgf[ni], accg[mi][ni], 0, 0, 0);
  }
  // LoRA up step
  __syncthreads();
  gload16(xdu + ((size_t)m0 + srow) * 32 + cs, xd0);
  gload16(xdu + ((size_t)m0 + srow + 64) * 32 + cs, xd1);
  gload16(Wuup + ((size_t)f0 + srow) * 32 + cs, ud0);
  gload16(Wuup + ((size_t)f0 + srow + 64) * 32 + cs, ud1);
  __syncthreads();
  {
    bf16x8 af[4], buf2[4];
#pragma unroll
    for (int i = 0; i < 4; ++i) {
      af[i]   = frag_ld(xs  + (wm * 64 + i * 16 + ml) * 32 + slotq);
      buf2[i] = frag_ld(wus + (wn * 64 + i * 16 + ml) * 32 + slotq);
    }
#pragma unroll
    for (int mi = 0; mi < 4; ++mi)
#pragma unroll
      for (int ni = 0; ni < 4; ++ni)
        accu[mi][ni] = __builtin_amdgcn_mfma_f32_16x16x32_bf16(af[mi], buf2[ni], accu[mi][ni], 0, 0, 0);
  }

  // epilogue: t = ERA(h_g) * h_u -> bf16
#pragma unroll
  for (int ni = 0; ni < 4; ++ni) {
    int col = f0 + wn * 64 + ni * 16 + ml;
    float cbg = bg[col] + SCALING * bgu[col];
    float cbu = bu[col] + SCALING * buu[col];
#pragma unroll
    for (int mi = 0; mi < 4; ++mi) {
      int row0 = m0 + wm * 64 + mi * 16 + q * 4;
#pragma unroll
      for (int r = 0; r < 4; ++r) {
        float hg = accg[mi][ni][r] + cbg;
        float hu = accu[mi][ni][r] + cbu;
        tout[(size_t)(row0 + r) * F_DIM + col] = f2bf(era_f(hg) * hu);
      }
    }
  }
}

// ---------------- down GEMM: out = t @ Wd + bd (fp32 out) ----------------
__global__ __launch_bounds__(256) void gemm_down(
    const ushort_t* __restrict__ tin, const ushort_t* __restrict__ Wdt,
    const float* __restrict__ bd, float* __restrict__ out) {
  __shared__ __align__(16) ushort_t as_[128 * 32];
  __shared__ __align__(16) ushort_t bs_[128 * 32];
  const int n0 = blockIdx.x * 128;
  const int m0 = blockIdx.y * 128;
  const int t = threadIdx.x;
  const int w = t >> 6, lane = t & 63;
  const int wm = w >> 1, wn = w & 1;
  const int ml = lane & 15, q = lane >> 4;

  const int srow = t >> 2;
  const int cs = ((t & 3) ^ ((srow >> 1) & 3)) * 8;
  const int slotq = (q ^ ((ml >> 1) & 3)) * 8;

  ushort_t* ad0 = as_ + w * 512;  ushort_t* ad1 = as_ + 2048 + w * 512;
  ushort_t* bd0 = bs_ + w * 512;  ushort_t* bd1 = bs_ + 2048 + w * 512;

  const f32x4 zero4 = {0.f, 0.f, 0.f, 0.f};
  f32x4 acc[4][4];
#pragma unroll
  for (int i = 0; i < 4; ++i)
#pragma unroll
    for (int j = 0; j < 4; ++j) acc[i][j] = zero4;

  const ushort_t* asrc0 = tin + (size_t)(m0 + srow) * F_DIM + cs;
  const ushort_t* asrc1 = asrc0 + (size_t)64 * F_DIM;
  const ushort_t* bsrc0 = Wdt + (size_t)(n0 + srow) * F_DIM + cs;
  const ushort_t* bsrc1 = bsrc0 + (size_t)64 * F_DIM;

  for (int kt = 0; kt < F_DIM / 32; ++kt) {
    const int ko = kt * 32;
    __syncthreads();
    gload16(asrc0 + ko, ad0);  gload16(asrc1 + ko, ad1);
    gload16(bsrc0 + ko, bd0);  gload16(bsrc1 + ko, bd1);
    __syncthreads();
    bf16x8 af[4], bf_[4];
#pragma unroll
    for (int i = 0; i < 4; ++i) {
      af[i]  = frag_ld(as_ + (wm * 64 + i * 16 + ml) * 32 + slotq);
      bf_[i] = frag_ld(bs_ + (wn * 64 + i * 16 + ml) * 32 + slotq);
    }
#pragma unroll
    for (int mi = 0; mi < 4; ++mi)
#pragma unroll
      for (int ni = 0; ni < 4; ++ni)
        acc[mi][ni] = __builtin_amdgcn_mfma_f32_16x16x32_bf16(af[mi], bf_[ni], acc[mi][ni], 0, 0, 0);
  }

#pragma unroll
  for (int ni = 0; ni < 4; ++ni) {
    int col = n0 + wn * 64 + ni * 16 + ml;
    float b = bd[col];
#pragma unroll
    for (int mi = 0; mi < 4; ++mi) {
      int row0 = m0 + wm * 64 + mi * 16 + q * 4;
#pragma unroll
      for (int r = 0; r < 4; ++r)
        out[(size_t)(row0 + r) * D_DIM + col] = acc[mi][ni][r] + b;
    }
  }
}

// ---------------- launcher ----------------

extern "C" void kernel_launch(void* const* d_in, const int* in_sizes, int n_in,
                              void* d_out, int out_size, void* d_ws, size_t ws_size,
                              hipStream_t stream) {
  const float* x   = (const float*)d_in[0];
  const float* Wg  = (const float*)d_in[1];
  const float* bg  = (const float*)d_in[2];
  const float* Wgd = (const float*)d_in[3];
  const float* bgd = (const float*)d_in[4];
  const float* Wgu = (const float*)d_in[5];
  const float* bgu = (const float*)d_in[6];
  const float* Wu  = (const float*)d_in[7];
  const float* bu  = (const float*)d_in[8];
  const float* Wud = (const float*)d_in[9];
  const float* bud = (const float*)d_in[10];
  const float* Wuu = (const float*)d_in[11];
  const float* buu = (const float*)d_in[12];
  const float* Wd  = (const float*)d_in[13];
  const float* bd  = (const float*)d_in[14];
  float* out = (float*)d_out;

  char* ws = (char*)d_ws;
  size_t off = 0;
  auto alloc = [&](size_t bytes) {
    char* p = ws + off;
    off += (bytes + 255) & ~(size_t)255;
    return p;
  };
  ushort_t* xbf  = (ushort_t*)alloc((size_t)M_DIM * D_DIM * 2);
  ushort_t* Wgt  = (ushort_t*)alloc((size_t)F_DIM * D_DIM * 2);
  ushort_t* Wut  = (ushort_t*)alloc((size_t)F_DIM * D_DIM * 2);
  ushort_t* Wdt  = (ushort_t*)alloc((size_t)D_DIM * F_DIM * 2);
  ushort_t* Wgup = (ushort_t*)alloc((size_t)F_DIM * 32 * 2);
  ushort_t* Wuup = (ushort_t*)alloc((size_t)F_DIM * 32 * 2);
  ushort_t* xdg  = (ushort_t*)alloc((size_t)M_DIM * 32 * 2);
  ushort_t* xdu  = (ushort_t*)alloc((size_t)M_DIM * 32 * 2);
  ushort_t* tbuf = (ushort_t*)alloc((size_t)M_DIM * F_DIM * 2);

  convert_x<<<(M_DIM * D_DIM / 4 + 255) / 256, 256, 0, stream>>>(x, xbf, M_DIM * D_DIM);
  transpose_w<<<dim3(F_DIM / 32, D_DIM / 32), 256, 0, stream>>>(Wg, Wgt, D_DIM, F_DIM);
  transpose_w<<<dim3(F_DIM / 32, D_DIM / 32), 256, 0, stream>>>(Wu, Wut, D_DIM, F_DIM);
  transpose_w<<<dim3(D_DIM / 32, F_DIM / 32), 256, 0, stream>>>(Wd, Wdt, F_DIM, D_DIM);
  pad_small<<<F_DIM * 32 / 256, 256, 0, stream>>>(Wgu, Wgup, F_DIM);
  pad_small<<<F_DIM * 32 / 256, 256, 0, stream>>>(Wuu, Wuup, F_DIM);
  lora_down<<<M_DIM / 8, 256, 0, stream>>>(x, Wgd, bgd, Wud, bud, xdg, xdu);
  gemm_gateup<<<dim3(F_DIM / 128, M_DIM / 128), 256, 0, stream>>>(
      xbf, Wgt, Wut, Wgup, Wuup, xdg, xdu, bg, bgu, bu, buu, tbuf);
  gemm_down<<<dim3(D_DIM / 128, M_DIM / 128), 256, 0, stream>>>(tbuf, Wdt, bd, out);
}

// Round 3
// 1457.924 us; speedup vs baseline: 1.3826x; 1.3826x over previous
//
#include <hip/hip_runtime.h>
#include <cstdint>
#include <cstddef>

#define D_DIM 2048
#define F_DIM 8192
#define M_DIM 8192   // 4 * 2048 tokens
#define SCALING 2.0f
#define GAMMA 0.1f
#define BUFE 4096    // ushorts per LDS tile buffer (128 rows x 32)

typedef __bf16 bf16x8 __attribute__((ext_vector_type(8)));
typedef float f32x4 __attribute__((ext_vector_type(4)));
typedef unsigned short ushort_t;

__device__ __forceinline__ unsigned short f2bf(float f) {
  unsigned int u = __float_as_uint(f);
  u += 0x7FFF + ((u >> 16) & 1);  // round-to-nearest-even
  return (unsigned short)(u >> 16);
}

__device__ __forceinline__ float era_f(float x) {
  // gelu_tanh(x) + GAMMA * softplus(x)
  float x3 = x * x * x;
  float inner = 0.7978845608028654f * (x + 0.044715f * x3);
  float e = __expf(2.0f * inner);
  float th = 1.0f - 2.0f / (e + 1.0f);       // tanh(inner), inf-safe
  float gelu = 0.5f * x * (1.0f + th);
  float sp = fmaxf(x, 0.0f) + __logf(1.0f + __expf(-fabsf(x)));
  return gelu + GAMMA * sp;
}

// ---------------- prep kernels ----------------

__global__ void convert_x(const float* __restrict__ in, ushort_t* __restrict__ out, int n) {
  int i = (blockIdx.x * 256 + threadIdx.x) * 4;
  if (i >= n) return;
  float4 v = *(const float4*)(in + i);
  out[i + 0] = f2bf(v.x);
  out[i + 1] = f2bf(v.y);
  out[i + 2] = f2bf(v.z);
  out[i + 3] = f2bf(v.w);
}

// in: fp32 [K][N] row-major  ->  out: bf16 [N][K]
__global__ void transpose_w(const float* __restrict__ in, ushort_t* __restrict__ out,
                            int K, int N) {
  __shared__ float tile[32][33];
  int k0 = blockIdx.y * 32, n0 = blockIdx.x * 32;
  int tr = threadIdx.x >> 5, tc = threadIdx.x & 31;
#pragma unroll
  for (int i = 0; i < 32; i += 8)
    tile[tr + i][tc] = in[(size_t)(k0 + tr + i) * N + n0 + tc];
  __syncthreads();
#pragma unroll
  for (int i = 0; i < 32; i += 8)
    out[(size_t)(n0 + tr + i) * K + k0 + tc] = f2bf(tile[tc][tr + i]);
}

// Wup fp32 [16][F] -> bf16 [F][32], k>=16 zero-padded
__global__ void pad_small(const float* __restrict__ in, ushort_t* __restrict__ out, int F) {
  int idx = blockIdx.x * 256 + threadIdx.x;  // F*32 total
  int f = idx >> 5, k = idx & 31;
  float v = (k < 16) ? in[(size_t)k * F + f] : 0.0f;
  out[idx] = f2bf(v);
}

// xd = SCALING * (x @ Wdn + bdn), stored bf16 [M][32] zero-padded; both g and u branches
__global__ void lora_down(const float* __restrict__ x,
                          const float* __restrict__ Wgd, const float* __restrict__ bgd,
                          const float* __restrict__ Wud, const float* __restrict__ bud,
                          ushort_t* __restrict__ xdg, ushort_t* __restrict__ xdu) {
  int row = blockIdx.x * 8 + (threadIdx.x >> 5);
  int c = threadIdx.x & 31;
  bool isG = (c < 16);
  int col = c & 15;
  const float* W = isG ? Wgd : Wud;
  const float* xr = x + (size_t)row * D_DIM;
  float acc = 0.0f;
  for (int k = 0; k < D_DIM; ++k)
    acc = fmaf(xr[k], W[k * 16 + col], acc);
  float b = isG ? bgd[col] : bud[col];
  ushort_t v = f2bf(SCALING * (acc + b));
  ushort_t* dst = isG ? xdg : xdu;
  dst[row * 32 + col] = v;
  dst[row * 32 + 16 + col] = 0;  // zero pad lanes k=16..31
}

// ---------------- GEMM helpers ----------------

// Direct global->LDS DMA, 16B per lane. LDS dest = wave-uniform base; lane i lands
// at base + i*16B. Global src is per-lane (carries the swizzle).
__device__ __forceinline__ void gload16(const ushort_t* g, ushort_t* l) {
  __builtin_amdgcn_global_load_lds(
      (__attribute__((address_space(1))) void*)g,
      (__attribute__((address_space(3))) void*)l, 16, 0, 0);
}

__device__ __forceinline__ bf16x8 frag_ld(const ushort_t* p) {
  union { uint4 u; bf16x8 v; } un;
  un.u = *(const uint4*)p;
  return un.v;
}

// LDS tile: linear [128][32] bf16 (64B rows, 4x16B chunks).
// XOR swizzle (both-sides): slot (row,c) holds global chunk c ^ ((row>>1)&3).
// DMA dest stays linear; the swizzle rides on the per-lane GLOBAL address and the
// ds_read address. Read banks: 16*ml + 4*((ml>>1)&3) mod 32 -> 2-way = free.

// ---------------- fused gate+up GEMM ----------------
// T3 minimum-2-phase pipeline: one __syncthreads per K-tile; prefetch tile t+1
// issued right after the barrier, so its vmcnt(0) drain (inside the NEXT barrier)
// happens a full compute-phase after issue. launch_bounds(256,2) keeps
// VGPR+AGPR <= 256 -> 2 waves/SIMD (the round-1 regression was 264 regs -> 1 wave).
__global__ __launch_bounds__(256, 2) void gemm_gateup(
    const ushort_t* __restrict__ xbf, const ushort_t* __restrict__ Wgt,
    const ushort_t* __restrict__ Wut, const ushort_t* __restrict__ Wgup,
    const ushort_t* __restrict__ Wuup, const ushort_t* __restrict__ xdg,
    const ushort_t* __restrict__ xdu,
    const float* __restrict__ bg, const float* __restrict__ bgu,
    const float* __restrict__ bu, const float* __restrict__ buu,
    ushort_t* __restrict__ tout) {
  __shared__ __align__(16) ushort_t xs[2 * BUFE];
  __shared__ __align__(16) ushort_t wgs[2 * BUFE];
  __shared__ __align__(16) ushort_t wus[2 * BUFE];
  const int f0 = blockIdx.x * 128;
  const int m0 = blockIdx.y * 128;
  const int t = threadIdx.x;
  const int w = t >> 6, lane = t & 63;
  const int wm = w >> 1, wn = w & 1;
  const int ml = lane & 15, q = lane >> 4;

  const int srow = t >> 2;                            // 0..63 (row within round)
  const int csw = ((t & 3) ^ ((srow >> 1) & 3)) * 8;  // swizzled chunk (ushorts)
  const int slotq = (q ^ ((ml >> 1) & 3)) * 8;        // read-side slot (per-thread const)
  const int dsto = w * 512;                           // wave's DMA dest offset

  // 32-bit per-lane offsets (ushort units), shared between the two W streams.
  unsigned int xoff = (unsigned int)(m0 + srow) * D_DIM + csw;
  unsigned int woff = (unsigned int)(f0 + srow) * D_DIM + csw;
  const unsigned int rstep = 64u * D_DIM;             // +64 rows
  const unsigned int lmo = (unsigned int)(m0 + srow) * 32 + csw;  // LoRA A offsets
  const unsigned int lfo = (unsigned int)(f0 + srow) * 32 + csw;  // LoRA B offsets

  auto stage_main = [&](int cur, unsigned int xo, unsigned int wo) {
    ushort_t* xd = xs + cur * BUFE + dsto;
    ushort_t* gd = wgs + cur * BUFE + dsto;
    ushort_t* ud = wus + cur * BUFE + dsto;
    gload16(xbf + xo, xd);  gload16(xbf + xo + rstep, xd + 2048);
    gload16(Wgt + wo, gd);  gload16(Wgt + wo + rstep, gd + 2048);
    gload16(Wut + wo, ud);  gload16(Wut + wo + rstep, ud + 2048);
  };
  auto stage_lora_g = [&](int cur) {
    ushort_t* xd = xs + cur * BUFE + dsto;
    ushort_t* gd = wgs + cur * BUFE + dsto;
    gload16(xdg + lmo, xd);   gload16(xdg + lmo + 2048, xd + 2048);
    gload16(Wgup + lfo, gd);  gload16(Wgup + lfo + 2048, gd + 2048);
  };
  auto stage_lora_u = [&](int cur) {
    ushort_t* xd = xs + cur * BUFE + dsto;
    ushort_t* ud = wus + cur * BUFE + dsto;
    gload16(xdu + lmo, xd);   gload16(xdu + lmo + 2048, xd + 2048);
    gload16(Wuup + lfo, ud);  gload16(Wuup + lfo + 2048, ud + 2048);
  };

  const f32x4 zero4 = {0.f, 0.f, 0.f, 0.f};
  f32x4 accg[4][4], accu[4][4];
#pragma unroll
  for (int i = 0; i < 4; ++i)
#pragma unroll
    for (int j = 0; j < 4; ++j) { accg[i][j] = zero4; accu[i][j] = zero4; }

  stage_main(0, xoff, woff);  // prologue: tile 0 -> buf 0

  const int NT = D_DIM / 32;  // 64
  for (int kt = 0; kt < NT; ++kt) {
    const int cur = kt & 1;
    xoff += 32; woff += 32;   // advance to tile kt+1
    __syncthreads();          // implicit vmcnt(0): tile kt landed; prev reads done
    if (kt < NT - 1) stage_main(cur ^ 1, xoff, woff);
    else             stage_lora_g(cur ^ 1);   // last iter prefetches LoRA-gate tile

    const ushort_t* xb = xs + cur * BUFE;
    const ushort_t* gb = wgs + cur * BUFE;
    const ushort_t* ub = wus + cur * BUFE;
    bf16x8 af[4], bwf[4];
#pragma unroll
    for (int i = 0; i < 4; ++i) {
      af[i]  = frag_ld(xb + (wm * 64 + i * 16 + ml) * 32 + slotq);
      bwf[i] = frag_ld(gb + (wn * 64 + i * 16 + ml) * 32 + slotq);
    }
#pragma unroll
    for (int mi = 0; mi < 4; ++mi)
#pragma unroll
      for (int ni = 0; ni < 4; ++ni)
        accg[mi][ni] = __builtin_amdgcn_mfma_f32_16x16x32_bf16(af[mi], bwf[ni], accg[mi][ni], 0, 0, 0);
#pragma unroll
    for (int i = 0; i < 4; ++i)
      bwf[i] = frag_ld(ub + (wn * 64 + i * 16 + ml) * 32 + slotq);
#pragma unroll
    for (int mi = 0; mi < 4; ++mi)
#pragma unroll
      for (int ni = 0; ni < 4; ++ni)
        accu[mi][ni] = __builtin_amdgcn_mfma_f32_16x16x32_bf16(af[mi], bwf[ni], accu[mi][ni], 0, 0, 0);
  }

  // LoRA gate step: data is in buf[ (NT)&1 == 0 ], prefetched during last main iter
  __syncthreads();
  stage_lora_u(1);            // prefetch LoRA-up tile into buf 1
  {
    bf16x8 af[4], bwf[4];
#pragma unroll
    for (int i = 0; i < 4; ++i) {
      af[i]  = frag_ld(xs  + (wm * 64 + i * 16 + ml) * 32 + slotq);
      bwf[i] = frag_ld(wgs + (wn * 64 + i * 16 + ml) * 32 + slotq);
    }
#pragma unroll
    for (int mi = 0; mi < 4; ++mi)
#pragma unroll
      for (int ni = 0; ni < 4; ++ni)
        accg[mi][ni] = __builtin_amdgcn_mfma_f32_16x16x32_bf16(af[mi], bwf[ni], accg[mi][ni], 0, 0, 0);
  }
  // LoRA up step from buf 1
  __syncthreads();
  {
    bf16x8 af[4], bwf[4];
#pragma unroll
    for (int i = 0; i < 4; ++i) {
      af[i]  = frag_ld(xs  + BUFE + (wm * 64 + i * 16 + ml) * 32 + slotq);
      bwf[i] = frag_ld(wus + BUFE + (wn * 64 + i * 16 + ml) * 32 + slotq);
    }
#pragma unroll
    for (int mi = 0; mi < 4; ++mi)
#pragma unroll
      for (int ni = 0; ni < 4; ++ni)
        accu[mi][ni] = __builtin_amdgcn_mfma_f32_16x16x32_bf16(af[mi], bwf[ni], accu[mi][ni], 0, 0, 0);
  }

  // epilogue: t = ERA(h_g) * h_u -> bf16
#pragma unroll
  for (int ni = 0; ni < 4; ++ni) {
    int col = f0 + wn * 64 + ni * 16 + ml;
    float cbg = bg[col] + SCALING * bgu[col];
    float cbu = bu[col] + SCALING * buu[col];
#pragma unroll
    for (int mi = 0; mi < 4; ++mi) {
      int row0 = m0 + wm * 64 + mi * 16 + q * 4;
#pragma unroll
      for (int r = 0; r < 4; ++r) {
        float hg = accg[mi][ni][r] + cbg;
        float hu = accu[mi][ni][r] + cbu;
        tout[(size_t)(row0 + r) * F_DIM + col] = f2bf(era_f(hg) * hu);
      }
    }
  }
}

// ---------------- down GEMM: out = t @ Wd + bd (fp32 out) ----------------
__global__ __launch_bounds__(256, 2) void gemm_down(
    const ushort_t* __restrict__ tin, const ushort_t* __restrict__ Wdt,
    const float* __restrict__ bd, float* __restrict__ out) {
  __shared__ __align__(16) ushort_t as_[2 * BUFE];
  __shared__ __align__(16) ushort_t bs_[2 * BUFE];
  const int n0 = blockIdx.x * 128;
  const int m0 = blockIdx.y * 128;
  const int t = threadIdx.x;
  const int w = t >> 6, lane = t & 63;
  const int wm = w >> 1, wn = w & 1;
  const int ml = lane & 15, q = lane >> 4;

  const int srow = t >> 2;
  const int csw = ((t & 3) ^ ((srow >> 1) & 3)) * 8;
  const int slotq = (q ^ ((ml >> 1) & 3)) * 8;
  const int dsto = w * 512;

  unsigned int aoff = (unsigned int)(m0 + srow) * F_DIM + csw;
  unsigned int boff = (unsigned int)(n0 + srow) * F_DIM + csw;
  const unsigned int rstep = 64u * F_DIM;

  auto stage = [&](int cur, unsigned int ao, unsigned int bo) {
    ushort_t* ad = as_ + cur * BUFE + dsto;
    ushort_t* bdst = bs_ + cur * BUFE + dsto;
    gload16(tin + ao, ad);   gload16(tin + ao + rstep, ad + 2048);
    gload16(Wdt + bo, bdst); gload16(Wdt + bo + rstep, bdst + 2048);
  };

  const f32x4 zero4 = {0.f, 0.f, 0.f, 0.f};
  f32x4 acc[4][4];
#pragma unroll
  for (int i = 0; i < 4; ++i)
#pragma unroll
    for (int j = 0; j < 4; ++j) acc[i][j] = zero4;

  stage(0, aoff, boff);

  const int NT = F_DIM / 32;  // 256
  for (int kt = 0; kt < NT; ++kt) {
    const int cur = kt & 1;
    aoff += 32; boff += 32;
    __syncthreads();
    if (kt < NT - 1) stage(cur ^ 1, aoff, boff);

    const ushort_t* ab = as_ + cur * BUFE;
    const ushort_t* bb = bs_ + cur * BUFE;
    bf16x8 af[4], bf_[4];
#pragma unroll
    for (int i = 0; i < 4; ++i) {
      af[i]  = frag_ld(ab + (wm * 64 + i * 16 + ml) * 32 + slotq);
      bf_[i] = frag_ld(bb + (wn * 64 + i * 16 + ml) * 32 + slotq);
    }
#pragma unroll
    for (int mi = 0; mi < 4; ++mi)
#pragma unroll
      for (int ni = 0; ni < 4; ++ni)
        acc[mi][ni] = __builtin_amdgcn_mfma_f32_16x16x32_bf16(af[mi], bf_[ni], acc[mi][ni], 0, 0, 0);
  }

#pragma unroll
  for (int ni = 0; ni < 4; ++ni) {
    int col = n0 + wn * 64 + ni * 16 + ml;
    float b = bd[col];
#pragma unroll
    for (int mi = 0; mi < 4; ++mi) {
      int row0 = m0 + wm * 64 + mi * 16 + q * 4;
#pragma unroll
      for (int r = 0; r < 4; ++r)
        out[(size_t)(row0 + r) * D_DIM + col] = acc[mi][ni][r] + b;
    }
  }
}

// ---------------- launcher ----------------

extern "C" void kernel_launch(void* const* d_in, const int* in_sizes, int n_in,
                              void* d_out, int out_size, void* d_ws, size_t ws_size,
                              hipStream_t stream) {
  const float* x   = (const float*)d_in[0];
  const float* Wg  = (const float*)d_in[1];
  const float* bg  = (const float*)d_in[2];
  const float* Wgd = (const float*)d_in[3];
  const float* bgd = (const float*)d_in[4];
  const float* Wgu = (const float*)d_in[5];
  const float* bgu = (const float*)d_in[6];
  const float* Wu  = (const float*)d_in[7];
  const float* bu  = (const float*)d_in[8];
  const float* Wud = (const float*)d_in[9];
  const float* bud = (const float*)d_in[10];
  const float* Wuu = (const float*)d_in[11];
  const float* buu = (const float*)d_in[12];
  const float* Wd  = (const float*)d_in[13];
  const float* bd  = (const float*)d_in[14];
  float* out = (float*)d_out;

  char* ws = (char*)d_ws;
  size_t off = 0;
  auto alloc = [&](size_t bytes) {
    char* p = ws + off;
    off += (bytes + 255) & ~(size_t)255;
    return p;
  };
  ushort_t* xbf  = (ushort_t*)alloc((size_t)M_DIM * D_DIM * 2);
  ushort_t* Wgt  = (ushort_t*)alloc((size_t)F_DIM * D_DIM * 2);
  ushort_t* Wut  = (ushort_t*)alloc((size_t)F_DIM * D_DIM * 2);
  ushort_t* Wdt  = (ushort_t*)alloc((size_t)D_DIM * F_DIM * 2);
  ushort_t* Wgup = (ushort_t*)alloc((size_t)F_DIM * 32 * 2);
  ushort_t* Wuup = (ushort_t*)alloc((size_t)F_DIM * 32 * 2);
  ushort_t* xdg  = (ushort_t*)alloc((size_t)M_DIM * 32 * 2);
  ushort_t* xdu  = (ushort_t*)alloc((size_t)M_DIM * 32 * 2);
  ushort_t* tbuf = (ushort_t*)alloc((size_t)M_DIM * F_DIM * 2);

  convert_x<<<(M_DIM * D_DIM / 4 + 255) / 256, 256, 0, stream>>>(x, xbf, M_DIM * D_DIM);
  transpose_w<<<dim3(F_DIM / 32, D_DIM / 32), 256, 0, stream>>>(Wg, Wgt, D_DIM, F_DIM);
  transpose_w<<<dim3(F_DIM / 32, D_DIM / 32), 256, 0, stream>>>(Wu, Wut, D_DIM, F_DIM);
  transpose_w<<<dim3(D_DIM / 32, F_DIM / 32), 256, 0, stream>>>(Wd, Wdt, F_DIM, D_DIM);
  pad_small<<<F_DIM * 32 / 256, 256, 0, stream>>>(Wgu, Wgup, F_DIM);
  pad_small<<<F_DIM * 32 / 256, 256, 0, stream>>>(Wuu, Wuup, F_DIM);
  lora_down<<<M_DIM / 8, 256, 0, stream>>>(x, Wgd, bgd, Wud, bud, xdg, xdu);
  gemm_gateup<<<dim3(F_DIM / 128, M_DIM / 128), 256, 0, stream>>>(
      xbf, Wgt, Wut, Wgup, Wuup, xdg, xdu, bg, bgu, bu, buu, tbuf);
  gemm_down<<<dim3(D_DIM / 128, M_DIM / 128), 256, 0, stream>>>(tbuf, Wdt, bd, out);
}

// Round 4
// 1457.914 us; speedup vs baseline: 1.3826x; 1.0000x over previous
//
#include <hip/hip_runtime.h>
#include <cstdint>
#include <cstddef>

#define D_DIM 2048
#define F_DIM 8192
#define M_DIM 8192   // 4 * 2048 tokens
#define SCALING 2.0f
#define GAMMA 0.1f
#define BUFE 4096    // ushorts per LDS tile buffer (128 rows x 32)

typedef __bf16 bf16x8 __attribute__((ext_vector_type(8)));
typedef float f32x4 __attribute__((ext_vector_type(4)));
typedef unsigned short ushort_t;

#define VMCNT(n) asm volatile("s_waitcnt vmcnt(" #n ")" ::: "memory")

__device__ __forceinline__ unsigned short f2bf(float f) {
  unsigned int u = __float_as_uint(f);
  u += 0x7FFF + ((u >> 16) & 1);  // round-to-nearest-even
  return (unsigned short)(u >> 16);
}

__device__ __forceinline__ float era_f(float x) {
  // gelu_tanh(x) + GAMMA * softplus(x)
  float x3 = x * x * x;
  float inner = 0.7978845608028654f * (x + 0.044715f * x3);
  float e = __expf(2.0f * inner);
  float th = 1.0f - 2.0f / (e + 1.0f);       // tanh(inner), inf-safe
  float gelu = 0.5f * x * (1.0f + th);
  float sp = fmaxf(x, 0.0f) + __logf(1.0f + __expf(-fabsf(x)));
  return gelu + GAMMA * sp;
}

// ---------------- prep kernels ----------------

__global__ void convert_x(const float* __restrict__ in, ushort_t* __restrict__ out, int n) {
  int i = (blockIdx.x * 256 + threadIdx.x) * 4;
  if (i >= n) return;
  float4 v = *(const float4*)(in + i);
  out[i + 0] = f2bf(v.x);
  out[i + 1] = f2bf(v.y);
  out[i + 2] = f2bf(v.z);
  out[i + 3] = f2bf(v.w);
}

// in: fp32 [K][N] row-major  ->  out: bf16 [N][K]
__global__ void transpose_w(const float* __restrict__ in, ushort_t* __restrict__ out,
                            int K, int N) {
  __shared__ float tile[32][33];
  int k0 = blockIdx.y * 32, n0 = blockIdx.x * 32;
  int tr = threadIdx.x >> 5, tc = threadIdx.x & 31;
#pragma unroll
  for (int i = 0; i < 32; i += 8)
    tile[tr + i][tc] = in[(size_t)(k0 + tr + i) * N + n0 + tc];
  __syncthreads();
#pragma unroll
  for (int i = 0; i < 32; i += 8)
    out[(size_t)(n0 + tr + i) * K + k0 + tc] = f2bf(tile[tc][tr + i]);
}

// Wup fp32 [16][F] -> bf16 [F][32], k>=16 zero-padded
__global__ void pad_small(const float* __restrict__ in, ushort_t* __restrict__ out, int F) {
  int idx = blockIdx.x * 256 + threadIdx.x;  // F*32 total
  int f = idx >> 5, k = idx & 31;
  float v = (k < 16) ? in[(size_t)k * F + f] : 0.0f;
  out[idx] = f2bf(v);
}

// xd = SCALING * (x @ Wdn + bdn), stored bf16 [M][32] zero-padded; both g and u branches
__global__ void lora_down(const float* __restrict__ x,
                          const float* __restrict__ Wgd, const float* __restrict__ bgd,
                          const float* __restrict__ Wud, const float* __restrict__ bud,
                          ushort_t* __restrict__ xdg, ushort_t* __restrict__ xdu) {
  int row = blockIdx.x * 8 + (threadIdx.x >> 5);
  int c = threadIdx.x & 31;
  bool isG = (c < 16);
  int col = c & 15;
  const float* W = isG ? Wgd : Wud;
  const float* xr = x + (size_t)row * D_DIM;
  float acc = 0.0f;
  for (int k = 0; k < D_DIM; ++k)
    acc = fmaf(xr[k], W[k * 16 + col], acc);
  float b = isG ? bgd[col] : bud[col];
  ushort_t v = f2bf(SCALING * (acc + b));
  ushort_t* dst = isG ? xdg : xdu;
  dst[row * 32 + col] = v;
  dst[row * 32 + 16 + col] = 0;  // zero pad lanes k=16..31
}

// ---------------- GEMM helpers ----------------

// Direct global->LDS DMA, 16B per lane. LDS dest = wave-uniform base; lane i lands
// at base + i*16B. Global src is per-lane (carries the swizzle).
__device__ __forceinline__ void gload16(const ushort_t* g, ushort_t* l) {
  __builtin_amdgcn_global_load_lds(
      (__attribute__((address_space(1))) void*)g,
      (__attribute__((address_space(3))) void*)l, 16, 0, 0);
}

__device__ __forceinline__ bf16x8 frag_ld(const ushort_t* p) {
  union { uint4 u; bf16x8 v; } un;
  un.u = *(const uint4*)p;
  return un.v;
}

// LDS tile: linear [128][32] bf16 (64B rows, 4x16B chunks).
// XOR swizzle (both-sides): slot (row,c) holds global chunk c ^ ((row>>1)&3).
// DMA dest stays linear; the swizzle rides on the per-lane GLOBAL address and the
// ds_read address. Read banks: 16*ml + 4*((ml>>1)&3) mod 32 -> 2-way = free.
//
// Pipeline (T3+T4): 3 LDS buffers, depth-2 prefetch, counted vmcnt (never 0 in
// the main loop). Per step s: wait vmcnt(loads(s+1)) -> tile s landed, tile s+1
// stays in flight; raw s_barrier; issue stage s+2; compute s. The asm "memory"
// clobbers order the gload_lds issues and block load hoisting across the waits,
// keeping the per-wave vmcnt arithmetic exact (no other vmem ops in the loop;
// ds_reads count against lgkmcnt, which the compiler manages).

// ---------------- fused gate+up GEMM ----------------
__global__ __launch_bounds__(256, 2) void gemm_gateup(
    const ushort_t* __restrict__ xbf, const ushort_t* __restrict__ Wgt,
    const ushort_t* __restrict__ Wut, const ushort_t* __restrict__ Wgup,
    const ushort_t* __restrict__ Wuup, const ushort_t* __restrict__ xdg,
    const ushort_t* __restrict__ xdu,
    const float* __restrict__ bg, const float* __restrict__ bgu,
    const float* __restrict__ bu, const float* __restrict__ buu,
    ushort_t* __restrict__ tout) {
  __shared__ __align__(16) ushort_t xs[3 * BUFE];
  __shared__ __align__(16) ushort_t wgs[3 * BUFE];
  __shared__ __align__(16) ushort_t wus[3 * BUFE];
  const int f0 = blockIdx.x * 128;
  const int m0 = blockIdx.y * 128;
  const int t = threadIdx.x;
  const int w = t >> 6, lane = t & 63;
  const int wm = w >> 1, wn = w & 1;
  const int ml = lane & 15, q = lane >> 4;

  const int srow = t >> 2;                            // 0..63 (row within round)
  const int csw = ((t & 3) ^ ((srow >> 1) & 3)) * 8;  // swizzled chunk (ushorts)
  const int slotq = (q ^ ((ml >> 1) & 3)) * 8;        // read-side slot (per-thread const)
  const int dsto = w * 512;                           // wave's DMA dest offset

  unsigned int xoff = (unsigned int)(m0 + srow) * D_DIM + csw;
  unsigned int woff = (unsigned int)(f0 + srow) * D_DIM + csw;
  const unsigned int rstep = 64u * D_DIM;             // +64 rows
  const unsigned int lmo = (unsigned int)(m0 + srow) * 32 + csw;  // LoRA A offsets
  const unsigned int lfo = (unsigned int)(f0 + srow) * 32 + csw;  // LoRA B offsets

  // 6 loads per main stage
  auto stage_main = [&](int bi, unsigned int xo, unsigned int wo) {
    ushort_t* xd = xs + bi * BUFE + dsto;
    ushort_t* gd = wgs + bi * BUFE + dsto;
    ushort_t* ud = wus + bi * BUFE + dsto;
    gload16(xbf + xo, xd);  gload16(xbf + xo + rstep, xd + 2048);
    gload16(Wgt + wo, gd);  gload16(Wgt + wo + rstep, gd + 2048);
    gload16(Wut + wo, ud);  gload16(Wut + wo + rstep, ud + 2048);
  };
  // 4 loads per LoRA stage
  auto stage_lora_g = [&](int bi) {
    ushort_t* xd = xs + bi * BUFE + dsto;
    ushort_t* gd = wgs + bi * BUFE + dsto;
    gload16(xdg + lmo, xd);   gload16(xdg + lmo + 2048, xd + 2048);
    gload16(Wgup + lfo, gd);  gload16(Wgup + lfo + 2048, gd + 2048);
  };
  auto stage_lora_u = [&](int bi) {
    ushort_t* xd = xs + bi * BUFE + dsto;
    ushort_t* ud = wus + bi * BUFE + dsto;
    gload16(xdu + lmo, xd);   gload16(xdu + lmo + 2048, xd + 2048);
    gload16(Wuup + lfo, ud);  gload16(Wuup + lfo + 2048, ud + 2048);
  };

  const f32x4 zero4 = {0.f, 0.f, 0.f, 0.f};
  f32x4 accg[4][4], accu[4][4];
#pragma unroll
  for (int i = 0; i < 4; ++i)
#pragma unroll
    for (int j = 0; j < 4; ++j) { accg[i][j] = zero4; accu[i][j] = zero4; }

  auto compute_main = [&](int bi) {
    const ushort_t* xb = xs + bi * BUFE;
    const ushort_t* gb = wgs + bi * BUFE;
    const ushort_t* ub = wus + bi * BUFE;
    bf16x8 af[4], bwf[4];
#pragma unroll
    for (int i = 0; i < 4; ++i) {
      af[i]  = frag_ld(xb + (wm * 64 + i * 16 + ml) * 32 + slotq);
      bwf[i] = frag_ld(gb + (wn * 64 + i * 16 + ml) * 32 + slotq);
    }
#pragma unroll
    for (int mi = 0; mi < 4; ++mi)
#pragma unroll
      for (int ni = 0; ni < 4; ++ni)
        accg[mi][ni] = __builtin_amdgcn_mfma_f32_16x16x32_bf16(af[mi], bwf[ni], accg[mi][ni], 0, 0, 0);
#pragma unroll
    for (int i = 0; i < 4; ++i)
      bwf[i] = frag_ld(ub + (wn * 64 + i * 16 + ml) * 32 + slotq);
#pragma unroll
    for (int mi = 0; mi < 4; ++mi)
#pragma unroll
      for (int ni = 0; ni < 4; ++ni)
        accu[mi][ni] = __builtin_amdgcn_mfma_f32_16x16x32_bf16(af[mi], bwf[ni], accu[mi][ni], 0, 0, 0);
  };
  auto compute_lora_g = [&](int bi) {
    bf16x8 af[4], bwf[4];
#pragma unroll
    for (int i = 0; i < 4; ++i) {
      af[i]  = frag_ld(xs  + bi * BUFE + (wm * 64 + i * 16 + ml) * 32 + slotq);
      bwf[i] = frag_ld(wgs + bi * BUFE + (wn * 64 + i * 16 + ml) * 32 + slotq);
    }
#pragma unroll
    for (int mi = 0; mi < 4; ++mi)
#pragma unroll
      for (int ni = 0; ni < 4; ++ni)
        accg[mi][ni] = __builtin_amdgcn_mfma_f32_16x16x32_bf16(af[mi], bwf[ni], accg[mi][ni], 0, 0, 0);
  };
  auto compute_lora_u = [&](int bi) {
    bf16x8 af[4], bwf[4];
#pragma unroll
    for (int i = 0; i < 4; ++i) {
      af[i]  = frag_ld(xs  + bi * BUFE + (wm * 64 + i * 16 + ml) * 32 + slotq);
      bwf[i] = frag_ld(wus + bi * BUFE + (wn * 64 + i * 16 + ml) * 32 + slotq);
    }
#pragma unroll
    for (int mi = 0; mi < 4; ++mi)
#pragma unroll
      for (int ni = 0; ni < 4; ++ni)
        accu[mi][ni] = __builtin_amdgcn_mfma_f32_16x16x32_bf16(af[mi], bwf[ni], accu[mi][ni], 0, 0, 0);
  };

  // prologue: tiles 0,1 -> bufs 0,1 (12 loads in flight)
  stage_main(0, xoff, woff);
  stage_main(1, xoff + 32, woff + 32);
  unsigned int xo_n = xoff + 64, wo_n = woff + 64;  // next stage = tile 2

  // steps 0..61: uniform vmcnt(6)
  int bc = 0, bs = 2;
#pragma unroll 1
  for (int kt = 0; kt < 62; ++kt) {
    VMCNT(6);
    __builtin_amdgcn_s_barrier();
    stage_main(bs, xo_n, wo_n);
    xo_n += 32; wo_n += 32;
    compute_main(bc);
    bc = (bc == 2) ? 0 : bc + 1;
    bs = (bs == 2) ? 0 : bs + 1;
  }
  // step 62: compute buf2, stage lora_g -> buf1
  VMCNT(6);
  __builtin_amdgcn_s_barrier();
  stage_lora_g(1);
  compute_main(2);
  // step 63: compute buf0, stage lora_u -> buf2
  VMCNT(4);
  __builtin_amdgcn_s_barrier();
  stage_lora_u(2);
  compute_main(0);
  // step 64: lora gate from buf1
  VMCNT(4);
  __builtin_amdgcn_s_barrier();
  compute_lora_g(1);
  // step 65: lora up from buf2
  VMCNT(0);
  __builtin_amdgcn_s_barrier();
  compute_lora_u(2);

  // epilogue: t = ERA(h_g) * h_u -> bf16
#pragma unroll
  for (int ni = 0; ni < 4; ++ni) {
    int col = f0 + wn * 64 + ni * 16 + ml;
    float cbg = bg[col] + SCALING * bgu[col];
    float cbu = bu[col] + SCALING * buu[col];
#pragma unroll
    for (int mi = 0; mi < 4; ++mi) {
      int row0 = m0 + wm * 64 + mi * 16 + q * 4;
#pragma unroll
      for (int r = 0; r < 4; ++r) {
        float hg = accg[mi][ni][r] + cbg;
        float hu = accu[mi][ni][r] + cbu;
        tout[(size_t)(row0 + r) * F_DIM + col] = f2bf(era_f(hg) * hu);
      }
    }
  }
}

// ---------------- down GEMM: out = t @ Wd + bd (fp32 out) ----------------
__global__ __launch_bounds__(256, 2) void gemm_down(
    const ushort_t* __restrict__ tin, const ushort_t* __restrict__ Wdt,
    const float* __restrict__ bd, float* __restrict__ out) {
  __shared__ __align__(16) ushort_t as_[3 * BUFE];
  __shared__ __align__(16) ushort_t bs_[3 * BUFE];
  const int n0 = blockIdx.x * 128;
  const int m0 = blockIdx.y * 128;
  const int t = threadIdx.x;
  const int w = t >> 6, lane = t & 63;
  const int wm = w >> 1, wn = w & 1;
  const int ml = lane & 15, q = lane >> 4;

  const int srow = t >> 2;
  const int csw = ((t & 3) ^ ((srow >> 1) & 3)) * 8;
  const int slotq = (q ^ ((ml >> 1) & 3)) * 8;
  const int dsto = w * 512;

  unsigned int aoff = (unsigned int)(m0 + srow) * F_DIM + csw;
  unsigned int boff = (unsigned int)(n0 + srow) * F_DIM + csw;
  const unsigned int rstep = 64u * F_DIM;

  auto stage = [&](int bi, unsigned int ao, unsigned int bo) {
    ushort_t* ad = as_ + bi * BUFE + dsto;
    ushort_t* bdst = bs_ + bi * BUFE + dsto;
    gload16(tin + ao, ad);   gload16(tin + ao + rstep, ad + 2048);
    gload16(Wdt + bo, bdst); gload16(Wdt + bo + rstep, bdst + 2048);
  };

  const f32x4 zero4 = {0.f, 0.f, 0.f, 0.f};
  f32x4 acc[4][4];
#pragma unroll
  for (int i = 0; i < 4; ++i)
#pragma unroll
    for (int j = 0; j < 4; ++j) acc[i][j] = zero4;

  auto compute = [&](int bi) {
    const ushort_t* ab = as_ + bi * BUFE;
    const ushort_t* bb = bs_ + bi * BUFE;
    bf16x8 af[4], bf_[4];
#pragma unroll
    for (int i = 0; i < 4; ++i) {
      af[i]  = frag_ld(ab + (wm * 64 + i * 16 + ml) * 32 + slotq);
      bf_[i] = frag_ld(bb + (wn * 64 + i * 16 + ml) * 32 + slotq);
    }
#pragma unroll
    for (int mi = 0; mi < 4; ++mi)
#pragma unroll
      for (int ni = 0; ni < 4; ++ni)
        acc[mi][ni] = __builtin_amdgcn_mfma_f32_16x16x32_bf16(af[mi], bf_[ni], acc[mi][ni], 0, 0, 0);
  };

  // prologue: tiles 0,1
  stage(0, aoff, boff);
  stage(1, aoff + 32, boff + 32);
  unsigned int ao_n = aoff + 64, bo_n = boff + 64;

  const int NT = F_DIM / 32;  // 256
  int bc = 0, bsn = 2;
#pragma unroll 1
  for (int kt = 0; kt < NT - 2; ++kt) {  // 254 steps
    VMCNT(4);
    __builtin_amdgcn_s_barrier();
    stage(bsn, ao_n, bo_n);
    ao_n += 32; bo_n += 32;
    compute(bc);
    bc = (bc == 2) ? 0 : bc + 1;
    bsn = (bsn == 2) ? 0 : bsn + 1;
  }
  // step NT-2 (254): compute buf2
  VMCNT(4);
  __builtin_amdgcn_s_barrier();
  compute(2);
  // step NT-1 (255): compute buf0
  VMCNT(0);
  __builtin_amdgcn_s_barrier();
  compute(0);

#pragma unroll
  for (int ni = 0; ni < 4; ++ni) {
    int col = n0 + wn * 64 + ni * 16 + ml;
    float b = bd[col];
#pragma unroll
    for (int mi = 0; mi < 4; ++mi) {
      int row0 = m0 + wm * 64 + mi * 16 + q * 4;
#pragma unroll
      for (int r = 0; r < 4; ++r)
        out[(size_t)(row0 + r) * D_DIM + col] = acc[mi][ni][r] + b;
    }
  }
}

// ---------------- launcher ----------------

extern "C" void kernel_launch(void* const* d_in, const int* in_sizes, int n_in,
                              void* d_out, int out_size, void* d_ws, size_t ws_size,
                              hipStream_t stream) {
  const float* x   = (const float*)d_in[0];
  const float* Wg  = (const float*)d_in[1];
  const float* bg  = (const float*)d_in[2];
  const float* Wgd = (const float*)d_in[3];
  const float* bgd = (const float*)d_in[4];
  const float* Wgu = (const float*)d_in[5];
  const float* bgu = (const float*)d_in[6];
  const float* Wu  = (const float*)d_in[7];
  const float* bu  = (const float*)d_in[8];
  const float* Wud = (const float*)d_in[9];
  const float* bud = (const float*)d_in[10];
  const float* Wuu = (const float*)d_in[11];
  const float* buu = (const float*)d_in[12];
  const float* Wd  = (const float*)d_in[13];
  const float* bd  = (const float*)d_in[14];
  float* out = (float*)d_out;

  char* ws = (char*)d_ws;
  size_t off = 0;
  auto alloc = [&](size_t bytes) {
    char* p = ws + off;
    off += (bytes + 255) & ~(size_t)255;
    return p;
  };
  ushort_t* xbf  = (ushort_t*)alloc((size_t)M_DIM * D_DIM * 2);
  ushort_t* Wgt  = (ushort_t*)alloc((size_t)F_DIM * D_DIM * 2);
  ushort_t* Wut  = (ushort_t*)alloc((size_t)F_DIM * D_DIM * 2);
  ushort_t* Wdt  = (ushort_t*)alloc((size_t)D_DIM * F_DIM * 2);
  ushort_t* Wgup = (ushort_t*)alloc((size_t)F_DIM * 32 * 2);
  ushort_t* Wuup = (ushort_t*)alloc((size_t)F_DIM * 32 * 2);
  ushort_t* xdg  = (ushort_t*)alloc((size_t)M_DIM * 32 * 2);
  ushort_t* xdu  = (ushort_t*)alloc((size_t)M_DIM * 32 * 2);
  ushort_t* tbuf = (ushort_t*)alloc((size_t)M_DIM * F_DIM * 2);

  convert_x<<<(M_DIM * D_DIM / 4 + 255) / 256, 256, 0, stream>>>(x, xbf, M_DIM * D_DIM);
  transpose_w<<<dim3(F_DIM / 32, D_DIM / 32), 256, 0, stream>>>(Wg, Wgt, D_DIM, F_DIM);
  transpose_w<<<dim3(F_DIM / 32, D_DIM / 32), 256, 0, stream>>>(Wu, Wut, D_DIM, F_DIM);
  transpose_w<<<dim3(D_DIM / 32, F_DIM / 32), 256, 0, stream>>>(Wd, Wdt, F_DIM, D_DIM);
  pad_small<<<F_DIM * 32 / 256, 256, 0, stream>>>(Wgu, Wgup, F_DIM);
  pad_small<<<F_DIM * 32 / 256, 256, 0, stream>>>(Wuu, Wuup, F_DIM);
  lora_down<<<M_DIM / 8, 256, 0, stream>>>(x, Wgd, bgd, Wud, bud, xdg, xdu);
  gemm_gateup<<<dim3(F_DIM / 128, M_DIM / 128), 256, 0, stream>>>(
      xbf, Wgt, Wut, Wgup, Wuup, xdg, xdu, bg, bgu, bu, buu, tbuf);
  gemm_down<<<dim3(D_DIM / 128, M_DIM / 128), 256, 0, stream>>>(tbuf, Wdt, bd, out);
}

// Round 5
// 1398.121 us; speedup vs baseline: 1.4417x; 1.0428x over previous
//
#include <hip/hip_runtime.h>
#include <cstdint>
#include <cstddef>

#define D_DIM 2048
#define F_DIM 8192
#define M_DIM 8192   // 4 * 2048 tokens
#define SCALING 2.0f
#define GAMMA 0.1f

typedef __bf16 bf16x8 __attribute__((ext_vector_type(8)));
typedef float f32x4 __attribute__((ext_vector_type(4)));
typedef unsigned short ushort_t;

#define VMCNT(n) asm volatile("s_waitcnt vmcnt(" #n ")" ::: "memory")

__device__ __forceinline__ unsigned short f2bf(float f) {
  unsigned int u = __float_as_uint(f);
  u += 0x7FFF + ((u >> 16) & 1);  // round-to-nearest-even
  return (unsigned short)(u >> 16);
}

__device__ __forceinline__ float era_f(float x) {
  // gelu_tanh(x) + GAMMA * softplus(x)
  float x3 = x * x * x;
  float inner = 0.7978845608028654f * (x + 0.044715f * x3);
  float e = __expf(2.0f * inner);
  float th = 1.0f - 2.0f / (e + 1.0f);       // tanh(inner), inf-safe
  float gelu = 0.5f * x * (1.0f + th);
  float sp = fmaxf(x, 0.0f) + __logf(1.0f + __expf(-fabsf(x)));
  return gelu + GAMMA * sp;
}

// ---------------- prep kernels ----------------

__global__ void convert_x(const float* __restrict__ in, ushort_t* __restrict__ out, int n) {
  int i = (blockIdx.x * 256 + threadIdx.x) * 4;
  if (i >= n) return;
  float4 v = *(const float4*)(in + i);
  out[i + 0] = f2bf(v.x);
  out[i + 1] = f2bf(v.y);
  out[i + 2] = f2bf(v.z);
  out[i + 3] = f2bf(v.w);
}

// in: fp32 [K][N] row-major  ->  out: bf16 [N][K]
__global__ void transpose_w(const float* __restrict__ in, ushort_t* __restrict__ out,
                            int K, int N) {
  __shared__ float tile[32][33];
  int k0 = blockIdx.y * 32, n0 = blockIdx.x * 32;
  int tr = threadIdx.x >> 5, tc = threadIdx.x & 31;
#pragma unroll
  for (int i = 0; i < 32; i += 8)
    tile[tr + i][tc] = in[(size_t)(k0 + tr + i) * N + n0 + tc];
  __syncthreads();
#pragma unroll
  for (int i = 0; i < 32; i += 8)
    out[(size_t)(n0 + tr + i) * K + k0 + tc] = f2bf(tile[tc][tr + i]);
}

// Wup fp32 [16][F] -> bf16 [F][32], k>=16 zero-padded
__global__ void pad_small(const float* __restrict__ in, ushort_t* __restrict__ out, int F) {
  int idx = blockIdx.x * 256 + threadIdx.x;  // F*32 total
  int f = idx >> 5, k = idx & 31;
  float v = (k < 16) ? in[(size_t)k * F + f] : 0.0f;
  out[idx] = f2bf(v);
}

// xd = SCALING * (x @ Wdn + bdn), stored bf16 [M][32] zero-padded; both g and u branches
__global__ void lora_down(const float* __restrict__ x,
                          const float* __restrict__ Wgd, const float* __restrict__ bgd,
                          const float* __restrict__ Wud, const float* __restrict__ bud,
                          ushort_t* __restrict__ xdg, ushort_t* __restrict__ xdu) {
  int row = blockIdx.x * 8 + (threadIdx.x >> 5);
  int c = threadIdx.x & 31;
  bool isG = (c < 16);
  int col = c & 15;
  const float* W = isG ? Wgd : Wud;
  const float* xr = x + (size_t)row * D_DIM;
  float acc = 0.0f;
  for (int k = 0; k < D_DIM; ++k)
    acc = fmaf(xr[k], W[k * 16 + col], acc);
  float b = isG ? bgd[col] : bud[col];
  ushort_t v = f2bf(SCALING * (acc + b));
  ushort_t* dst = isG ? xdg : xdu;
  dst[row * 32 + col] = v;
  dst[row * 32 + 16 + col] = 0;  // zero pad lanes k=16..31
}

// ---------------- GEMM helpers ----------------

// Direct global->LDS DMA, 16B per lane. LDS dest = wave-uniform base; lane i lands
// at base + i*16B. Global src is per-lane (carries the swizzle).
__device__ __forceinline__ void gload16(const ushort_t* g, ushort_t* l) {
  __builtin_amdgcn_global_load_lds(
      (__attribute__((address_space(1))) void*)g,
      (__attribute__((address_space(3))) void*)l, 16, 0, 0);
}

__device__ __forceinline__ bf16x8 frag_ld(const ushort_t* p) {
  union { uint4 u; bf16x8 v; } un;
  un.u = *(const uint4*)p;
  return un.v;
}

// LDS tiles: linear [rows][32] bf16 (64B rows, 4x16B chunks). XOR swizzle
// (both-sides): slot (row,c) holds global chunk c ^ ((row>>1)&3); the swizzle
// rides on the per-lane GLOBAL src address (DMA dest stays lane-linear) and on
// the ds_read address. Read banks: 2-way = free.
//
// Schedule (T3+T4+T5, 256-tile template adapted): 512 thr / 8 waves, BK=32,
// 3-buffer ring, depth-2 prefetch. Per K-tile: {VMCNT(4); barrier;
// phase1: ds_read A+Bg frags | issue A-stage of tile t+2 | setprio(1) 16 MFMA;
// barrier; phase2: ds_read Bu | issue B-stage | setprio(1) 16 MFMA}. vmcnt
// never drains to 0 in the main loop; tile t's loads (issued at t-2) are
// published by the top vmcnt+barrier pair.

// ---------------- fused gate+up GEMM ----------------
// BM=256 (m), BN=128 (f). Wave grid 4M x 2N; per-wave 64x64 out per branch.
__global__ __launch_bounds__(512, 2) void gemm_gateup(
    const ushort_t* __restrict__ xbf, const ushort_t* __restrict__ Wgt,
    const ushort_t* __restrict__ Wut, const ushort_t* __restrict__ Wgup,
    const ushort_t* __restrict__ Wuup, const ushort_t* __restrict__ xdg,
    const ushort_t* __restrict__ xdu,
    const float* __restrict__ bg, const float* __restrict__ bgu,
    const float* __restrict__ bu, const float* __restrict__ buu,
    ushort_t* __restrict__ tout) {
  __shared__ __align__(16) ushort_t lA[3 * 8192];   // [256][32] per buf
  __shared__ __align__(16) ushort_t lBg[3 * 4096];  // [128][32] per buf
  __shared__ __align__(16) ushort_t lBu[3 * 4096];
  const int f0 = blockIdx.x * 128;
  const int m0 = blockIdx.y * 256;
  const int t = threadIdx.x;
  const int w = t >> 6, lane = t & 63;
  const int wm = w >> 1, wn = w & 1;            // 4M x 2N
  const int ml = lane & 15, q = lane >> 4;

  const int srow = t >> 2;                            // 0..127
  const int csw = ((t & 3) ^ ((srow >> 1) & 3)) * 8;  // swizzled chunk (ushorts)
  const int slotq = (q ^ ((ml >> 1) & 3)) * 8;        // read-side slot
  const int dstw = w * 512;                           // wave DMA dest offset in a round

  unsigned int xoff = (unsigned int)(m0 + srow) * D_DIM + csw;  // A rows (round0)
  unsigned int woff = (unsigned int)(f0 + srow) * D_DIM + csw;  // B rows 0..127
  const unsigned int arstep = 128u * D_DIM;
  const unsigned int lmo = (unsigned int)(m0 + srow) * 32 + csw;  // LoRA A
  const unsigned int lfo = (unsigned int)(f0 + srow) * 32 + csw;  // LoRA B

  // A stage: 2 rounds (rows 0-127, 128-255)
  auto stageA = [&](int bi, unsigned int ko) {
    ushort_t* d = lA + bi * 8192 + dstw;
    gload16(xbf + xoff + ko, d);
    gload16(xbf + xoff + arstep + ko, d + 4096);
  };
  auto stageB = [&](int bi, unsigned int ko) {
    gload16(Wgt + woff + ko, lBg + bi * 4096 + dstw);
    gload16(Wut + woff + ko, lBu + bi * 4096 + dstw);
  };
  auto stageLoraA_g = [&](int bi) {
    ushort_t* d = lA + bi * 8192 + dstw;
    gload16(xdg + lmo, d);
    gload16(xdg + lmo + 128u * 32, d + 4096);
  };
  auto stageLoraB_g = [&](int bi) { gload16(Wgup + lfo, lBg + bi * 4096 + dstw); };
  auto stageLoraA_u = [&](int bi) {
    ushort_t* d = lA + bi * 8192 + dstw;
    gload16(xdu + lmo, d);
    gload16(xdu + lmo + 128u * 32, d + 4096);
  };
  auto stageLoraB_u = [&](int bi) { gload16(Wuup + lfo, lBu + bi * 4096 + dstw); };

  const f32x4 zero4 = {0.f, 0.f, 0.f, 0.f};
  f32x4 accg[4][4], accu[4][4];
#pragma unroll
  for (int i = 0; i < 4; ++i)
#pragma unroll
    for (int j = 0; j < 4; ++j) { accg[i][j] = zero4; accu[i][j] = zero4; }

  bf16x8 af[4], bwf[4];
  auto loadA = [&](int bi) {
#pragma unroll
    for (int i = 0; i < 4; ++i)
      af[i] = frag_ld(lA + bi * 8192 + (wm * 64 + i * 16 + ml) * 32 + slotq);
  };
  auto loadBg = [&](int bi) {
#pragma unroll
    for (int i = 0; i < 4; ++i)
      bwf[i] = frag_ld(lBg + bi * 4096 + (wn * 64 + i * 16 + ml) * 32 + slotq);
  };
  auto loadBu = [&](int bi) {
#pragma unroll
    for (int i = 0; i < 4; ++i)
      bwf[i] = frag_ld(lBu + bi * 4096 + (wn * 64 + i * 16 + ml) * 32 + slotq);
  };
  auto mfmaG = [&]() {
    __builtin_amdgcn_s_setprio(1);
#pragma unroll
    for (int mi = 0; mi < 4; ++mi)
#pragma unroll
      for (int ni = 0; ni < 4; ++ni)
        accg[mi][ni] = __builtin_amdgcn_mfma_f32_16x16x32_bf16(af[mi], bwf[ni], accg[mi][ni], 0, 0, 0);
    __builtin_amdgcn_s_setprio(0);
  };
  auto mfmaU = [&]() {
    __builtin_amdgcn_s_setprio(1);
#pragma unroll
    for (int mi = 0; mi < 4; ++mi)
#pragma unroll
      for (int ni = 0; ni < 4; ++ni)
        accu[mi][ni] = __builtin_amdgcn_mfma_f32_16x16x32_bf16(af[mi], bwf[ni], accu[mi][ni], 0, 0, 0);
    __builtin_amdgcn_s_setprio(0);
  };

  // prologue: tiles 0,1 -> bufs 0,1 (8 loads in flight, queue order A0 B0 A1 B1)
  stageA(0, 0);  stageB(0, 0);
  stageA(1, 32); stageB(1, 32);

  int bc = 0, bs = 2;
  unsigned int ko = 64;  // k-offset of tile kt+2
#pragma unroll 1
  for (int kt = 0; kt < 62; ++kt) {
    VMCNT(4);                       // tile kt landed; kt+1 in flight
    __builtin_amdgcn_s_barrier();   // publish buf bc
    // phase 1: gate
    loadA(bc); loadBg(bc);
    stageA(bs, ko);
    mfmaG();
    __builtin_amdgcn_s_barrier();
    // phase 2: up
    loadBu(bc);
    stageB(bs, ko);
    mfmaU();
    ko += 32;
    bc = (bc == 2) ? 0 : bc + 1;
    bs = (bs == 2) ? 0 : bs + 1;
  }
  // kt=62: compute buf 2, stage LoRA-gate -> buf 1 (3 loads)
  VMCNT(4);
  __builtin_amdgcn_s_barrier();
  loadA(2); loadBg(2);
  stageLoraA_g(1);
  mfmaG();
  __builtin_amdgcn_s_barrier();
  loadBu(2);
  stageLoraB_g(1);
  mfmaU();
  // kt=63: compute buf 0, stage LoRA-up -> buf 2 (3 loads)
  VMCNT(3);
  __builtin_amdgcn_s_barrier();
  loadA(0); loadBg(0);
  stageLoraA_u(2);
  mfmaG();
  __builtin_amdgcn_s_barrier();
  loadBu(0);
  stageLoraB_u(2);
  mfmaU();
  // tile 64: LoRA gate from buf 1
  VMCNT(3);
  __builtin_amdgcn_s_barrier();
  loadA(1); loadBg(1);
  mfmaG();
  // tile 65: LoRA up from buf 2
  VMCNT(0);
  __builtin_amdgcn_s_barrier();
  loadA(2); loadBu(2);
  mfmaU();

  // epilogue: t = ERA(h_g) * h_u -> bf16
#pragma unroll
  for (int ni = 0; ni < 4; ++ni) {
    int col = f0 + wn * 64 + ni * 16 + ml;
    float cbg = bg[col] + SCALING * bgu[col];
    float cbu = bu[col] + SCALING * buu[col];
#pragma unroll
    for (int mi = 0; mi < 4; ++mi) {
      int row0 = m0 + wm * 64 + mi * 16 + q * 4;
#pragma unroll
      for (int r = 0; r < 4; ++r) {
        float hg = accg[mi][ni][r] + cbg;
        float hu = accu[mi][ni][r] + cbu;
        tout[(size_t)(row0 + r) * F_DIM + col] = f2bf(era_f(hg) * hu);
      }
    }
  }
}

// ---------------- down GEMM: out = t @ Wd + bd (fp32 out) ----------------
// BM=256 (m), BN=256 (n). Wave grid 4M x 2N; per-wave 64x128 out, acc[4][8].
__global__ __launch_bounds__(512, 2) void gemm_down(
    const ushort_t* __restrict__ tin, const ushort_t* __restrict__ Wdt,
    const float* __restrict__ bd, float* __restrict__ out) {
  __shared__ __align__(16) ushort_t lA[3 * 8192];  // [256][32] per buf
  __shared__ __align__(16) ushort_t lB[3 * 8192];  // [256][32] per buf
  const int n0 = blockIdx.x * 256;
  const int m0 = blockIdx.y * 256;
  const int t = threadIdx.x;
  const int w = t >> 6, lane = t & 63;
  const int wm = w >> 1, wn = w & 1;
  const int ml = lane & 15, q = lane >> 4;

  const int srow = t >> 2;
  const int csw = ((t & 3) ^ ((srow >> 1) & 3)) * 8;
  const int slotq = (q ^ ((ml >> 1) & 3)) * 8;
  const int dstw = w * 512;

  unsigned int aoff = (unsigned int)(m0 + srow) * F_DIM + csw;
  unsigned int boff = (unsigned int)(n0 + srow) * F_DIM + csw;
  const unsigned int arstep = 128u * F_DIM;

  auto stageA = [&](int bi, unsigned int ko) {
    ushort_t* d = lA + bi * 8192 + dstw;
    gload16(tin + aoff + ko, d);
    gload16(tin + aoff + arstep + ko, d + 4096);
  };
  auto stageB = [&](int bi, unsigned int ko) {
    ushort_t* d = lB + bi * 8192 + dstw;
    gload16(Wdt + boff + ko, d);
    gload16(Wdt + boff + arstep + ko, d + 4096);
  };

  const f32x4 zero4 = {0.f, 0.f, 0.f, 0.f};
  f32x4 acc[4][8];
#pragma unroll
  for (int i = 0; i < 4; ++i)
#pragma unroll
    for (int j = 0; j < 8; ++j) acc[i][j] = zero4;

  bf16x8 af[4], bf_[4];
  auto loadA = [&](int bi) {
#pragma unroll
    for (int i = 0; i < 4; ++i)
      af[i] = frag_ld(lA + bi * 8192 + (wm * 64 + i * 16 + ml) * 32 + slotq);
  };
  auto loadB = [&](int bi, int half) {
#pragma unroll
    for (int i = 0; i < 4; ++i)
      bf_[i] = frag_ld(lB + bi * 8192 + (wn * 128 + half * 64 + i * 16 + ml) * 32 + slotq);
  };
  auto mfmaH = [&](int half) {
    __builtin_amdgcn_s_setprio(1);
#pragma unroll
    for (int mi = 0; mi < 4; ++mi)
#pragma unroll
      for (int ni = 0; ni < 4; ++ni)
        acc[mi][half * 4 + ni] =
            __builtin_amdgcn_mfma_f32_16x16x32_bf16(af[mi], bf_[ni], acc[mi][half * 4 + ni], 0, 0, 0);
    __builtin_amdgcn_s_setprio(0);
  };

  // prologue: tiles 0,1
  stageA(0, 0);  stageB(0, 0);
  stageA(1, 32); stageB(1, 32);

  const int NT = F_DIM / 32;  // 256
  int bc = 0, bs = 2;
  unsigned int ko = 64;
#pragma unroll 1
  for (int kt = 0; kt < NT - 2; ++kt) {  // 254 steps
    VMCNT(4);
    __builtin_amdgcn_s_barrier();
    // phase 1: B cols 0..63 of wave's half
    loadA(bc); loadB(bc, 0);
    stageA(bs, ko);
    mfmaH(0);
    __builtin_amdgcn_s_barrier();
    // phase 2: B cols 64..127
    loadB(bc, 1);
    stageB(bs, ko);
    mfmaH(1);
    ko += 32;
    bc = (bc == 2) ? 0 : bc + 1;
    bs = (bs == 2) ? 0 : bs + 1;
  }
  // kt = 254: compute, no stage
  VMCNT(4);
  __builtin_amdgcn_s_barrier();
  loadA(bc); loadB(bc, 0);
  mfmaH(0);
  __builtin_amdgcn_s_barrier();
  loadB(bc, 1);
  mfmaH(1);
  bc = (bc == 2) ? 0 : bc + 1;
  // kt = 255
  VMCNT(0);
  __builtin_amdgcn_s_barrier();
  loadA(bc); loadB(bc, 0);
  mfmaH(0);
  loadB(bc, 1);
  mfmaH(1);

#pragma unroll
  for (int ni = 0; ni < 8; ++ni) {
    int col = n0 + wn * 128 + ni * 16 + ml;
    float b = bd[col];
#pragma unroll
    for (int mi = 0; mi < 4; ++mi) {
      int row0 = m0 + wm * 64 + mi * 16 + q * 4;
#pragma unroll
      for (int r = 0; r < 4; ++r)
        out[(size_t)(row0 + r) * D_DIM + col] = acc[mi][ni][r] + b;
    }
  }
}

// ---------------- launcher ----------------

extern "C" void kernel_launch(void* const* d_in, const int* in_sizes, int n_in,
                              void* d_out, int out_size, void* d_ws, size_t ws_size,
                              hipStream_t stream) {
  const float* x   = (const float*)d_in[0];
  const float* Wg  = (const float*)d_in[1];
  const float* bg  = (const float*)d_in[2];
  const float* Wgd = (const float*)d_in[3];
  const float* bgd = (const float*)d_in[4];
  const float* Wgu = (const float*)d_in[5];
  const float* bgu = (const float*)d_in[6];
  const float* Wu  = (const float*)d_in[7];
  const float* bu  = (const float*)d_in[8];
  const float* Wud = (const float*)d_in[9];
  const float* bud = (const float*)d_in[10];
  const float* Wuu = (const float*)d_in[11];
  const float* buu = (const float*)d_in[12];
  const float* Wd  = (const float*)d_in[13];
  const float* bd  = (const float*)d_in[14];
  float* out = (float*)d_out;

  char* ws = (char*)d_ws;
  size_t off = 0;
  auto alloc = [&](size_t bytes) {
    char* p = ws + off;
    off += (bytes + 255) & ~(size_t)255;
    return p;
  };
  ushort_t* xbf  = (ushort_t*)alloc((size_t)M_DIM * D_DIM * 2);
  ushort_t* Wgt  = (ushort_t*)alloc((size_t)F_DIM * D_DIM * 2);
  ushort_t* Wut  = (ushort_t*)alloc((size_t)F_DIM * D_DIM * 2);
  ushort_t* Wdt  = (ushort_t*)alloc((size_t)D_DIM * F_DIM * 2);
  ushort_t* Wgup = (ushort_t*)alloc((size_t)F_DIM * 32 * 2);
  ushort_t* Wuup = (ushort_t*)alloc((size_t)F_DIM * 32 * 2);
  ushort_t* xdg  = (ushort_t*)alloc((size_t)M_DIM * 32 * 2);
  ushort_t* xdu  = (ushort_t*)alloc((size_t)M_DIM * 32 * 2);
  ushort_t* tbuf = (ushort_t*)alloc((size_t)M_DIM * F_DIM * 2);

  convert_x<<<(M_DIM * D_DIM / 4 + 255) / 256, 256, 0, stream>>>(x, xbf, M_DIM * D_DIM);
  transpose_w<<<dim3(F_DIM / 32, D_DIM / 32), 256, 0, stream>>>(Wg, Wgt, D_DIM, F_DIM);
  transpose_w<<<dim3(F_DIM / 32, D_DIM / 32), 256, 0, stream>>>(Wu, Wut, D_DIM, F_DIM);
  transpose_w<<<dim3(D_DIM / 32, F_DIM / 32), 256, 0, stream>>>(Wd, Wdt, F_DIM, D_DIM);
  pad_small<<<F_DIM * 32 / 256, 256, 0, stream>>>(Wgu, Wgup, F_DIM);
  pad_small<<<F_DIM * 32 / 256, 256, 0, stream>>>(Wuu, Wuup, F_DIM);
  lora_down<<<M_DIM / 8, 256, 0, stream>>>(x, Wgd, bgd, Wud, bud, xdg, xdu);
  gemm_gateup<<<dim3(F_DIM / 128, M_DIM / 256), 512, 0, stream>>>(
      xbf, Wgt, Wut, Wgup, Wuup, xdg, xdu, bg, bgu, bu, buu, tbuf);
  gemm_down<<<dim3(D_DIM / 256, M_DIM / 256), 512, 0, stream>>>(tbuf, Wdt, bd, out);
}